// Round 1
// baseline (47.737 us; speedup 1.0000x reference)
//
#include <hip/hip_runtime.h>

#define NNODES 2048
#define NHEADS 8
#define NN (NNODES * NNODES)

// Pass 1: resolve duplicate (row,col) scatters as last-edge-index-wins
// (matches numpy fancy-assignment / XLA CPU scatter-set ordering).
__global__ __launch_bounds__(256) void winner_kernel(const int* __restrict__ ei, int E,
                                                     int* __restrict__ winner) {
    int e = blockIdx.x * blockDim.x + threadIdx.x;
    if (e >= E) return;
    int row = ei[e];        // edge_index[0][e]
    int col = ei[E + e];    // edge_index[1][e]
    atomicMax(&winner[row * NNODES + col], e);
}

// Pass 2: dense write of the full (H, N, N) output. Each thread owns 4
// consecutive cells (one row, since N % 4 == 0), writes one float4 per head
// (coalesced per-wave per-head). Non-edge cells get 0.0f — so no separate
// output zero-fill is needed; every output element is written exactly once.
__global__ __launch_bounds__(256) void write_kernel(const int* __restrict__ winner,
                                                    const float* __restrict__ edge_score,
                                                    const float* __restrict__ W,
                                                    const float* __restrict__ b,
                                                    float* __restrict__ out) {
    int t = blockIdx.x * blockDim.x + threadIdx.x;
    int cell0 = t << 2;
    if (cell0 >= NN) return;

    const int4 w4 = *reinterpret_cast<const int4*>(winner + cell0);
    const int wi[4] = {w4.x, w4.y, w4.z, w4.w};

    const float row  = (float)(cell0 >> 11);            // cell0 / 2048
    const float colb = (float)(cell0 & (NNODES - 1));   // cell0 % 2048

    // Gather scores only where an edge exists (poison/empty = negative index).
    float sc[4];
#pragma unroll
    for (int i = 0; i < 4; ++i) sc[i] = (wi[i] >= 0) ? edge_score[wi[i]] : 0.0f;

#pragma unroll
    for (int h = 0; h < NHEADS; ++h) {
        const float W0 = W[h * 3 + 0];   // uniform -> scalar loads, L2/SMEM cached
        const float W1 = W[h * 3 + 1];
        const float W2 = W[h * 3 + 2];
        const float B  = b[h];
        float4 v;
        float* vp = reinterpret_cast<float*>(&v);
#pragma unroll
        for (int i = 0; i < 4; ++i) {
            const float x = fmaf(row, W0, fmaf(colb + (float)i, W1, fmaf(sc[i], W2, B)));
            const float s = 1.0f / (1.0f + __expf(-x));
            vp[i] = (wi[i] >= 0) ? s : 0.0f;
        }
        *reinterpret_cast<float4*>(out + (size_t)h * NN + cell0) = v;
    }
}

extern "C" void kernel_launch(void* const* d_in, const int* in_sizes, int n_in,
                              void* d_out, int out_size, void* d_ws, size_t ws_size,
                              hipStream_t stream) {
    const int*   edge_index = (const int*)d_in[0];   // (2, E) int32
    const float* edge_score = (const float*)d_in[1]; // (E,)
    const float* W          = (const float*)d_in[2]; // (H, 3)
    const float* b          = (const float*)d_in[3]; // (H,)
    float*       out        = (float*)d_out;         // (H, N, N)
    const int E = in_sizes[1];

    int* winner = (int*)d_ws;  // N*N ints = 16 MiB scratch

    // Init winner to -1 every call (deterministic; ws poison is 0xAA).
    hipMemsetAsync(winner, 0xFF, (size_t)NN * sizeof(int), stream);

    winner_kernel<<<(E + 255) / 256, 256, 0, stream>>>(edge_index, E, winner);

    write_kernel<<<NN / (4 * 256), 256, 0, stream>>>(winner, edge_score, W, b, out);
}